// Round 1
// baseline (76.714 us; speedup 1.0000x reference)
//
#include <hip/hip_runtime.h>

// BatchRankingLoss: loss = sum_{i,j} w_ij * max(0, 1 + y_ij*(o_i - o_j)) / (B*(B-1))
//   y_ij = sign(t_i - t_j)  (tie convention irrelevant: weight is 0 when |ld| <= 0.1)
//   w_ij = |t_i - t_j| > 0.1
// B = 8192. Inputs: o [B,1] fp32, t [B] fp32. Output: [1] fp32.

constexpr int BLOCK  = 256;   // threads per block, one i per thread
constexpr int JCHUNK = 256;   // j elements per block (staged in LDS)
constexpr float GAP = 1.0f;
constexpr float THRESHOLD = 0.1f;

__global__ void zero_ws_kernel(float* ws) {
    ws[0] = 0.0f;
}

__global__ __launch_bounds__(BLOCK) void pair_loss_kernel(
        const float* __restrict__ o, const float* __restrict__ t,
        float* __restrict__ ws, int B) {
    __shared__ float so[JCHUNK];
    __shared__ float st[JCHUNK];

    const int tid = threadIdx.x;
    const int i   = blockIdx.x * BLOCK + tid;
    const int j0  = blockIdx.y * JCHUNK;

    // stage this block's j-chunk into LDS (coalesced 4B/lane loads)
    so[tid] = o[j0 + tid];
    st[tid] = t[j0 + tid];
    __syncthreads();

    const float oi = o[i];
    const float ti = t[i];

    float acc = 0.0f;
#pragma unroll 8
    for (int j = 0; j < JCHUNK; ++j) {
        // same-address LDS reads across the wave -> broadcast, no bank conflict
        const float ld   = ti - st[j];
        const float diff = oi - so[j];
        const float y    = copysignf(1.0f, ld);
        const float h    = fmaxf(0.0f, fmaf(y, diff, GAP));
        acc += (fabsf(ld) > THRESHOLD) ? h : 0.0f;
    }

    // wave (64-lane) shuffle reduction
    for (int off = 32; off > 0; off >>= 1)
        acc += __shfl_down(acc, off, 64);

    __shared__ float wsum[BLOCK / 64];
    if ((tid & 63) == 0) wsum[tid >> 6] = acc;
    __syncthreads();

    if (tid == 0) {
        float s = 0.0f;
#pragma unroll
        for (int w = 0; w < BLOCK / 64; ++w) s += wsum[w];
        atomicAdd(ws, s);  // device-scope by default on CDNA
    }
}

__global__ void finalize_kernel(const float* __restrict__ ws,
                                float* __restrict__ out, int B) {
    const float N = (float)((long long)B * (long long)(B - 1));
    out[0] = ws[0] / N;
}

extern "C" void kernel_launch(void* const* d_in, const int* in_sizes, int n_in,
                              void* d_out, int out_size, void* d_ws, size_t ws_size,
                              hipStream_t stream) {
    const float* o = (const float*)d_in[0];   // input  [B,1] fp32
    const float* t = (const float*)d_in[1];   // gdt_ts [B]   fp32
    float* out = (float*)d_out;
    float* ws  = (float*)d_ws;

    const int B = in_sizes[1];                // 8192

    zero_ws_kernel<<<1, 1, 0, stream>>>(ws);

    dim3 grid(B / BLOCK, B / JCHUNK);         // 32 x 32 = 1024 blocks
    pair_loss_kernel<<<grid, BLOCK, 0, stream>>>(o, t, ws, B);

    finalize_kernel<<<1, 1, 0, stream>>>(ws, out, B);
}

// Round 2
// 69.894 us; speedup vs baseline: 1.0976x; 1.0976x over previous
//
#include <hip/hip_runtime.h>

// BatchRankingLoss: loss = sum_{i,j} w_ij * max(0, 1 + y_ij*(o_i - o_j)) / (B*(B-1))
//   y_ij = sign(t_i - t_j)   (tie convention irrelevant: weight 0 when |ld| <= 0.1)
//   w_ij = |t_i - t_j| > 0.1
// B = 8192. Inputs: o [B,1] fp32, t [B] fp32. Output: [1] fp32.
//
// Structure: grid.x tiles i (BLOCK threads x TILE_I each), grid.y tiles j
// (JCHUNK staged in LDS, broadcast-read, amortized over TILE_I i's per thread).
// Each block writes one fp32 partial to d_ws; a second kernel reduces.

constexpr int BLOCK  = 256;
constexpr int TILE_I = 4;     // i's per thread (registers)
constexpr int JCHUNK = 64;    // j's per block (LDS)
constexpr float GAP = 1.0f;
constexpr float THRESHOLD = 0.1f;

__global__ __launch_bounds__(BLOCK) void pair_loss_kernel(
        const float* __restrict__ o, const float* __restrict__ t,
        float* __restrict__ partials) {
    __shared__ float so[JCHUNK];
    __shared__ float st[JCHUNK];

    const int tid = threadIdx.x;
    const int j0  = blockIdx.y * JCHUNK;

    // stage j-chunk (threads 0..63 load o, 64..127 load t)
    if (tid < JCHUNK)                 so[tid] = o[j0 + tid];
    else if (tid < 2 * JCHUNK)        st[tid - JCHUNK] = t[j0 + tid - JCHUNK];
    __syncthreads();

    // this thread's TILE_I i-values (strided by BLOCK -> coalesced loads)
    const int ibase = blockIdx.x * (BLOCK * TILE_I) + tid;
    float oi[TILE_I], ti[TILE_I];
#pragma unroll
    for (int k = 0; k < TILE_I; ++k) {
        oi[k] = o[ibase + k * BLOCK];
        ti[k] = t[ibase + k * BLOCK];
    }

    float acc[TILE_I] = {0.f, 0.f, 0.f, 0.f};
#pragma unroll 8
    for (int j = 0; j < JCHUNK; ++j) {
        const float oj = so[j];   // wave-uniform broadcast, conflict-free
        const float tj = st[j];
#pragma unroll
        for (int k = 0; k < TILE_I; ++k) {
            const float ld   = ti[k] - tj;
            const float diff = oi[k] - oj;
            // y*diff = diff with sign flipped iff ld < 0  (ties gated out by w)
            const unsigned sgn = __float_as_uint(ld) & 0x80000000u;
            const float yd  = __uint_as_float(__float_as_uint(diff) ^ sgn);
            const float s   = GAP + yd;
            acc[k] += (fabsf(ld) > THRESHOLD) ? fmaxf(s, 0.0f) : 0.0f;
        }
    }

    float a = (acc[0] + acc[1]) + (acc[2] + acc[3]);
    // wave64 shuffle reduction
    for (int off = 32; off > 0; off >>= 1)
        a += __shfl_down(a, off, 64);

    __shared__ float wsum[BLOCK / 64];
    if ((tid & 63) == 0) wsum[tid >> 6] = a;
    __syncthreads();

    if (tid == 0) {
        float s = 0.0f;
#pragma unroll
        for (int w = 0; w < BLOCK / 64; ++w) s += wsum[w];
        partials[blockIdx.y * gridDim.x + blockIdx.x] = s;
    }
}

__global__ __launch_bounds__(BLOCK) void reduce_kernel(
        const float* __restrict__ partials, float* __restrict__ out,
        int nblk, int B) {
    const int tid = threadIdx.x;
    float a = 0.0f;
    for (int p = tid; p < nblk; p += BLOCK) a += partials[p];

    for (int off = 32; off > 0; off >>= 1)
        a += __shfl_down(a, off, 64);

    __shared__ float wsum[BLOCK / 64];
    if ((tid & 63) == 0) wsum[tid >> 6] = a;
    __syncthreads();

    if (tid == 0) {
        float s = 0.0f;
#pragma unroll
        for (int w = 0; w < BLOCK / 64; ++w) s += wsum[w];
        const float N = (float)((long long)B * (long long)(B - 1));
        out[0] = s / N;
    }
}

extern "C" void kernel_launch(void* const* d_in, const int* in_sizes, int n_in,
                              void* d_out, int out_size, void* d_ws, size_t ws_size,
                              hipStream_t stream) {
    const float* o = (const float*)d_in[0];   // input  [B,1] fp32
    const float* t = (const float*)d_in[1];   // gdt_ts [B]   fp32
    float* out = (float*)d_out;
    float* ws  = (float*)d_ws;

    const int B = in_sizes[1];                // 8192

    dim3 grid(B / (BLOCK * TILE_I), B / JCHUNK);   // 8 x 128 = 1024 blocks
    pair_loss_kernel<<<grid, BLOCK, 0, stream>>>(o, t, ws);

    const int nblk = grid.x * grid.y;
    reduce_kernel<<<1, BLOCK, 0, stream>>>(ws, out, nblk, B);
}